// Round 6
// baseline (177.131 us; speedup 1.0000x reference)
//
#include <hip/hip_runtime.h>
#include <hip/hip_bf16.h>

#define NROWS 8192
#define DDIM  256
#define INV_TEMP 20.0f   // 1/0.05

typedef __attribute__((ext_vector_type(8)))  short bf16x8;
typedef __attribute__((ext_vector_type(16))) float f32x16;

// ---------------------------------------------------------------------------
// Fragment-major layout (bf16 elements), used for BOTH qn and pn:
//   row r, elem e:  s=e>>4 (kstep), h=(e>>3)&1, j=e&7, cb=r>>5, c=r&31
//   elem offset = (((s*256 + cb)*2 + h)*32 + c)*8 + j
// One (cb,s) block = 512 elems = 1 KB contiguous; MFMA 32x32x16 A/B fragment
// = lane l reads 8 elems at block_base + l*8 -> one coalesced dwordx4/lane.
// Verified correct in r5 (passed, absmax 0).
// ---------------------------------------------------------------------------

// ---------------------------------------------------------------------------
// Kernel 1: per-row L2-normalize q,p (fp32), write bf16 fragment-major,
// fp32 diag, zero lse + counter. One wave/row, 4 rows/256-thr block.
// ---------------------------------------------------------------------------
__global__ __launch_bounds__(256) void norm_diag_kernel(
    const float* __restrict__ q, const float* __restrict__ p,
    unsigned short* __restrict__ qn, unsigned short* __restrict__ pn,
    float* __restrict__ diag, float* __restrict__ lse,
    unsigned int* __restrict__ counter)
{
    const int row  = blockIdx.x * 4 + (threadIdx.x >> 6);
    const int lane = threadIdx.x & 63;

    const float4 qv = ((const float4*)(q + (size_t)row * DDIM))[lane];
    const float4 pv = ((const float4*)(p + (size_t)row * DDIM))[lane];

    float sq = qv.x*qv.x + qv.y*qv.y + qv.z*qv.z + qv.w*qv.w;
    float sp = pv.x*pv.x + pv.y*pv.y + pv.z*pv.z + pv.w*pv.w;
    #pragma unroll
    for (int m = 1; m < 64; m <<= 1) {
        sq += __shfl_xor(sq, m);
        sp += __shfl_xor(sp, m);
    }
    const float qs = 1.0f / fmaxf(sqrtf(sq), 1e-8f);
    const float ps = 1.0f / fmaxf(sqrtf(sp), 1e-8f);

    const float qx = qv.x*qs, qy = qv.y*qs, qz = qv.z*qs, qw = qv.w*qs;
    const float px = pv.x*ps, py = pv.y*ps, pz = pv.z*ps, pw = pv.w*ps;

    float d = qx*px + qy*py + qz*pz + qw*pw;
    #pragma unroll
    for (int m = 1; m < 64; m <<= 1) d += __shfl_xor(d, m);
    if (lane == 0) {
        diag[row] = d * INV_TEMP;
        lse[row]  = 0.0f;              // ws re-poisoned every call
    }
    if (blockIdx.x == 0 && threadIdx.x == 0) *counter = 0u;

    union { unsigned short u16[4]; uint2 v; } uq, up;
    {
        __hip_bfloat16 b;
        b = __float2bfloat16(qx); uq.u16[0] = *(unsigned short*)&b;
        b = __float2bfloat16(qy); uq.u16[1] = *(unsigned short*)&b;
        b = __float2bfloat16(qz); uq.u16[2] = *(unsigned short*)&b;
        b = __float2bfloat16(qw); uq.u16[3] = *(unsigned short*)&b;
        b = __float2bfloat16(px); up.u16[0] = *(unsigned short*)&b;
        b = __float2bfloat16(py); up.u16[1] = *(unsigned short*)&b;
        b = __float2bfloat16(pz); up.u16[2] = *(unsigned short*)&b;
        b = __float2bfloat16(pw); up.u16[3] = *(unsigned short*)&b;
    }
    // lane's 4 elems: e0=4*lane -> s=lane>>2, h=(lane>>1)&1, jbyte=8*(lane&1)
    const int s = lane >> 2, h = (lane >> 1) & 1;
    const int cb = row >> 5, c = row & 31;
    const size_t dst = ((size_t)(s * 256 + cb) << 10) + (h << 9) + (c << 4)
                     + ((lane & 1) << 3);
    *(uint2*)((char*)qn + dst) = uq.v;
    *(uint2*)((char*)pn + dst) = up.v;
}

// ---------------------------------------------------------------------------
// Kernel 2: barrier-free fused GEMM + sum-exp + (last block) final loss.
// Rebalanced for latency tolerance: wave owns 32 rows (A = 16 frags = 64
// VGPR, loaded once), streams B fragments through a depth-8 rolling register
// buffer (32 VGPR) -> ~130-150 total regs -> 3 waves/SIMD (24 outstanding
// 1-KB loads per SIMD). All 4 waves of a block walk the SAME B sequence ->
// L1 reuse. One acc chain per col-block; exp epilogue per col-block.
// 32x32x16 layouts: A lane row=l&31, k=(l>>5)*8+j; B same with col=l&31;
// C/D col=l&31, row=(reg&3)+8*(reg>>2)+4*(l>>5)  [m74/m101, r5-verified].
// No max-subtraction: |sim|<=20.5 -> lse < 4e12 fits fp32.
// Prefetch addresses stay inside pn (max block idx 2048 < 4096): no guard.
// ---------------------------------------------------------------------------
__global__ __launch_bounds__(256, 3) void simexp_kernel(
    const unsigned short* __restrict__ qn,
    const unsigned short* __restrict__ pn,
    float* __restrict__ lse, const float* __restrict__ diag,
    unsigned int* __restrict__ counter, float* __restrict__ out)
{
    __shared__ float wsum[4];
    __shared__ unsigned int is_last;

    const int tid  = threadIdx.x;
    const int lane = tid & 63;
    const int w    = tid >> 6;
    const int rowstart = blockIdx.y * 128 + w * 32;   // wave's 32 rows
    const int cbA = blockIdx.y * 4 + w;               // A col-block
    const int cb0 = blockIdx.x * 16;                  // 16 B col-blocks (512 cols)

    // --- A: one 32-row tile, full K=256 -> 16 fragments = 64 VGPR ---
    bf16x8 a[16];
    #pragma unroll
    for (int s = 0; s < 16; ++s)
        a[s] = *(const bf16x8*)(qn + ((size_t)(s * 256 + cbA) << 9) + lane * 8);

    const unsigned short* bbase = pn + lane * 8;
    // fragment f (0..255): col-block cb = cb0 + (f>>4), kstep s = f&15
    #define FRAG(f) (*(const bf16x8*)(bbase + \
        ((size_t)((((f) & 15) << 8) + cb0 + ((f) >> 4)) << 9)))

    // depth-8 rolling prefetch buffer
    bf16x8 bq[8];
    #pragma unroll
    for (int i = 0; i < 8; ++i) bq[i] = FRAG(i);

    f32x16 lsum = (f32x16)0.0f;

    for (int cbi = 0; cbi < 16; ++cbi) {
        f32x16 acc = (f32x16)0.0f;
        #pragma unroll
        for (int s = 0; s < 16; ++s) {
            acc = __builtin_amdgcn_mfma_f32_32x32x16_bf16(a[s], bq[s & 7], acc, 0, 0, 0);
            const int fn = cbi * 16 + s + 8;          // prefetch distance 8
            bq[s & 7] = FRAG(fn);                     // always in-bounds of pn
        }
        #pragma unroll
        for (int r = 0; r < 16; ++r)
            lsum[r] += __expf(acc[r] * INV_TEMP);
    }
    #undef FRAG

    // --- reduce over 32 col-lanes per half; 16 atomicAdds per half-wave ---
    #pragma unroll
    for (int r = 0; r < 16; ++r) {
        float v = lsum[r];
        #pragma unroll
        for (int m = 1; m < 32; m <<= 1) v += __shfl_xor(v, m);
        if ((lane & 31) == 0) {
            const int rl = (r & 3) + 8 * (r >> 2) + ((lane >> 5) << 2);
            atomicAdd(&lse[rowstart + rl], v);
        }
    }

    // --- completion: last block computes the final loss ---
    __threadfence();
    __syncthreads();
    if (tid == 0) {
        const unsigned int nblk = gridDim.x * gridDim.y;
        is_last = (atomicAdd(counter, 1u) == nblk - 1u);
    }
    __syncthreads();
    if (is_last) {
        __threadfence();
        float s = 0.0f;
        for (int i = tid; i < NROWS; i += 256) {
            float v = __hip_atomic_load(&lse[i], __ATOMIC_RELAXED,
                                        __HIP_MEMORY_SCOPE_AGENT);
            s += __logf(v) - diag[i];
        }
        #pragma unroll
        for (int m = 1; m < 64; m <<= 1) s += __shfl_xor(s, m);
        if (lane == 0) wsum[w] = s;
        __syncthreads();
        if (tid == 0)
            out[0] = (wsum[0] + wsum[1] + wsum[2] + wsum[3]) * (1.0f / NROWS);
    }
}

// ---------------------------------------------------------------------------
extern "C" void kernel_launch(void* const* d_in, const int* in_sizes, int n_in,
                              void* d_out, int out_size, void* d_ws, size_t ws_size,
                              hipStream_t stream)
{
    const float* q = (const float*)d_in[0];
    const float* p = (const float*)d_in[1];

    char* ws = (char*)d_ws;
    unsigned short* qn = (unsigned short*)ws;                          // 4 MB
    unsigned short* pn = (unsigned short*)(ws + (size_t)NROWS*DDIM*2); // 4 MB
    float* diag = (float*)(ws + 2 * (size_t)NROWS * DDIM * 2);         // 32 KB
    float* lse  = diag + NROWS;                                        // 32 KB
    unsigned int* counter = (unsigned int*)(lse + NROWS);              // 4 B

    norm_diag_kernel<<<NROWS / 4, 256, 0, stream>>>(q, p, qn, pn, diag, lse, counter);

    dim3 grid(16, 64);   // colgroups(512 cols) x rowblocks(128 rows) = 1024 blocks
    simexp_kernel<<<grid, 256, 0, stream>>>(qn, pn, lse, diag, counter, (float*)d_out);
}

// Round 7
// 173.647 us; speedup vs baseline: 1.0201x; 1.0201x over previous
//
#include <hip/hip_runtime.h>
#include <hip/hip_bf16.h>

#define NROWS 8192
#define DDIM  256
#define INV_TEMP 20.0f   // 1/0.05

typedef __attribute__((ext_vector_type(8)))  short bf16x8;
typedef __attribute__((ext_vector_type(16))) float f32x16;

// async global->LDS, 16B per lane. LDS dest = wave-uniform base + lane*16.
__device__ static inline void async16(const void* g, void* l) {
    __builtin_amdgcn_global_load_lds(
        (const __attribute__((address_space(1))) void*)g,
        (__attribute__((address_space(3))) void*)l, 16, 0, 0);
}

// ---------------------------------------------------------------------------
// qn layout: fragment-major for 32x32x16 A-fragments (r5/r6-verified):
//   row r, elem e: s=e>>4, h=(e>>3)&1, j=e&7, cb=r>>5, c=r&31
//   elem offset = (((s*256+cb)*2+h)*32+c)*8+j ; one (cb,s) block = 1 KB.
// pn layout: plain row-major (B staged to LDS by k-slices).
// ---------------------------------------------------------------------------

// ---------------------------------------------------------------------------
// Kernel 1: per-row L2-normalize q,p (fp32); qn fragment-major, pn row-major;
// fp32 diag; zero lse + counter. One wave/row, 4 rows per 256-thr block.
// ---------------------------------------------------------------------------
__global__ __launch_bounds__(256) void norm_diag_kernel(
    const float* __restrict__ q, const float* __restrict__ p,
    unsigned short* __restrict__ qn, unsigned short* __restrict__ pn,
    float* __restrict__ diag, float* __restrict__ lse,
    unsigned int* __restrict__ counter)
{
    const int row  = blockIdx.x * 4 + (threadIdx.x >> 6);
    const int lane = threadIdx.x & 63;

    const float4 qv = ((const float4*)(q + (size_t)row * DDIM))[lane];
    const float4 pv = ((const float4*)(p + (size_t)row * DDIM))[lane];

    float sq = qv.x*qv.x + qv.y*qv.y + qv.z*qv.z + qv.w*qv.w;
    float sp = pv.x*pv.x + pv.y*pv.y + pv.z*pv.z + pv.w*pv.w;
    #pragma unroll
    for (int m = 1; m < 64; m <<= 1) {
        sq += __shfl_xor(sq, m);
        sp += __shfl_xor(sp, m);
    }
    const float qs = 1.0f / fmaxf(sqrtf(sq), 1e-8f);
    const float ps = 1.0f / fmaxf(sqrtf(sp), 1e-8f);

    const float qx = qv.x*qs, qy = qv.y*qs, qz = qv.z*qs, qw = qv.w*qs;
    const float px = pv.x*ps, py = pv.y*ps, pz = pv.z*ps, pw = pv.w*ps;

    float d = qx*px + qy*py + qz*pz + qw*pw;
    #pragma unroll
    for (int m = 1; m < 64; m <<= 1) d += __shfl_xor(d, m);
    if (lane == 0) {
        diag[row] = d * INV_TEMP;
        lse[row]  = 0.0f;              // ws re-poisoned every call
    }
    if (blockIdx.x == 0 && threadIdx.x == 0) *counter = 0u;

    union { unsigned short u16[4]; uint2 v; } uq, up;
    {
        __hip_bfloat16 b;
        b = __float2bfloat16(qx); uq.u16[0] = *(unsigned short*)&b;
        b = __float2bfloat16(qy); uq.u16[1] = *(unsigned short*)&b;
        b = __float2bfloat16(qz); uq.u16[2] = *(unsigned short*)&b;
        b = __float2bfloat16(qw); uq.u16[3] = *(unsigned short*)&b;
        b = __float2bfloat16(px); up.u16[0] = *(unsigned short*)&b;
        b = __float2bfloat16(py); up.u16[1] = *(unsigned short*)&b;
        b = __float2bfloat16(pz); up.u16[2] = *(unsigned short*)&b;
        b = __float2bfloat16(pw); up.u16[3] = *(unsigned short*)&b;
    }
    // qn fragment-major: lane's 4 elems e0=4*lane -> s=lane>>2, h=(lane>>1)&1
    const int s = lane >> 2, h = (lane >> 1) & 1;
    const int cb = row >> 5, c = row & 31;
    const size_t dst = ((size_t)(s * 256 + cb) << 10) + (h << 9) + (c << 4)
                     + ((lane & 1) << 3);
    *(uint2*)((char*)qn + dst) = uq.v;
    // pn row-major
    *(uint2*)(pn + (size_t)row * DDIM + lane * 4) = up.v;
}

// ---------------------------------------------------------------------------
// Kernel 2: fused GEMM + sum-exp + (last block) final loss.
// Block = 4 waves; wave owns 32 rows: A = 16 fragment-major 32x32x16 frags
// (64 VGPR), loaded once, coalesced. Block covers 128 rows x 512 cols as
// 16 chunks of 32 cols. Per chunk: stage B (32 P-rows x 512 B = 16 KB) into
// single-buffer LDS (4 async16/lane), barrier, 16 MFMAs/wave (512 SIMD-cyc).
// 16 KB LDS -> 4 blocks/CU resident (grid 1024 = one full generation);
// each SIMD hosts 4 waves from 4 DIFFERENT blocks at independent phases, so
// one block's vmcnt(0) drain is covered by the other three (m114 overlap).
// LDS layout: k-step s at s*1024, within: lane-linear 16 B pieces, so both
// the async16 dest (uniform + lane*16) and the B-fragment ds_read_b128
// (s*1024 + lane*16) are exact.  32x32x16 C/D: col=lane&31,
// row=(r&3)+8*(r>>2)+4*(lane>>5)  [m74/m101, r5/r6-verified].
// exp without max-subtraction: |sim|<=20.5 -> lse < 4e12, fits fp32.
// ---------------------------------------------------------------------------
__global__ __launch_bounds__(256, 4) void simexp_kernel(
    const unsigned short* __restrict__ qn,
    const unsigned short* __restrict__ pn,
    float* __restrict__ lse, const float* __restrict__ diag,
    unsigned int* __restrict__ counter, float* __restrict__ out)
{
    __shared__ unsigned char lds[16384];
    __shared__ float wsum[4];
    __shared__ unsigned int is_last;

    const int tid  = threadIdx.x;
    const int lane = tid & 63;
    const int w    = tid >> 6;
    const int rowstart = blockIdx.y * 128 + w * 32;   // wave's 32 rows
    const int cbA = blockIdx.y * 4 + w;               // A row-block (qn frag-major)
    const int colbase = blockIdx.x * 512;

    // --- A: one 32-row tile, full K=256 -> 16 frags = 64 VGPR, coalesced ---
    bf16x8 a[16];
    #pragma unroll
    for (int s = 0; s < 16; ++s)
        a[s] = *(const bf16x8*)(qn + ((size_t)(s * 256 + cbA) << 9) + lane * 8);

    // --- B staging: per chunk, lane stages 4 x 16 B.
    // piece q = i*256 + tid -> col=lane&31, khalf=lane>>5, kstep=i*4+w.
    const unsigned short* sB = pn + (size_t)(colbase + (lane & 31)) * DDIM
                             + w * 16 + (lane >> 5) * 8;
    unsigned char* ldsD = lds + w * 1024 + lane * 16;

    f32x16 lsum = (f32x16)0.0f;

    for (int c = 0; c < 16; ++c) {
        __syncthreads();               // prev chunk's ds_reads complete
        #pragma unroll
        for (int i = 0; i < 4; ++i)
            async16(sB + (size_t)c * 32 * DDIM + i * 64, ldsD + i * 4096);
        __syncthreads();               // staging drained

        f32x16 acc = (f32x16)0.0f;
        #pragma unroll
        for (int s = 0; s < 16; ++s) {
            const bf16x8 bf = *(const bf16x8*)(lds + s * 1024 + lane * 16);
            acc = __builtin_amdgcn_mfma_f32_32x32x16_bf16(a[s], bf, acc, 0, 0, 0);
        }
        #pragma unroll
        for (int r = 0; r < 16; ++r)
            lsum[r] += __expf(acc[r] * INV_TEMP);
    }

    // --- reduce over 32 col-lanes per half; one atomicAdd per row-reg ---
    #pragma unroll
    for (int r = 0; r < 16; ++r) {
        float v = lsum[r];
        #pragma unroll
        for (int m = 1; m < 32; m <<= 1) v += __shfl_xor(v, m);
        if ((lane & 31) == 0) {
            const int rl = (r & 3) + 8 * (r >> 2) + ((lane >> 5) << 2);
            atomicAdd(&lse[rowstart + rl], v);
        }
    }

    // --- completion: last block computes the final loss ---
    __threadfence();
    __syncthreads();
    if (tid == 0) {
        const unsigned int nblk = gridDim.x * gridDim.y;
        is_last = (atomicAdd(counter, 1u) == nblk - 1u);
    }
    __syncthreads();
    if (is_last) {
        __threadfence();
        float s = 0.0f;
        for (int i = tid; i < NROWS; i += 256) {
            float v = __hip_atomic_load(&lse[i], __ATOMIC_RELAXED,
                                        __HIP_MEMORY_SCOPE_AGENT);
            s += __logf(v) - diag[i];
        }
        #pragma unroll
        for (int m = 1; m < 64; m <<= 1) s += __shfl_xor(s, m);
        if (lane == 0) wsum[w] = s;
        __syncthreads();
        if (tid == 0)
            out[0] = (wsum[0] + wsum[1] + wsum[2] + wsum[3]) * (1.0f / NROWS);
    }
}

// ---------------------------------------------------------------------------
extern "C" void kernel_launch(void* const* d_in, const int* in_sizes, int n_in,
                              void* d_out, int out_size, void* d_ws, size_t ws_size,
                              hipStream_t stream)
{
    const float* q = (const float*)d_in[0];
    const float* p = (const float*)d_in[1];

    char* ws = (char*)d_ws;
    unsigned short* qn = (unsigned short*)ws;                          // 4 MB
    unsigned short* pn = (unsigned short*)(ws + (size_t)NROWS*DDIM*2); // 4 MB
    float* diag = (float*)(ws + 2 * (size_t)NROWS * DDIM * 2);         // 32 KB
    float* lse  = diag + NROWS;                                        // 32 KB
    unsigned int* counter = (unsigned int*)(lse + NROWS);              // 4 B

    norm_diag_kernel<<<NROWS / 4, 256, 0, stream>>>(q, p, qn, pn, diag, lse, counter);

    dim3 grid(16, 64);   // colgroups(512) x rowgroups(128) = 1024 blocks, 4/CU
    simexp_kernel<<<grid, 256, 0, stream>>>(qn, pn, lse, diag, counter, (float*)d_out);
}